// Round 1
// baseline (524.722 us; speedup 1.0000x reference)
//
#include <hip/hip_runtime.h>
#include <math.h>

// Problem constants
#define NSIG 64          // 2 inputs x 32 batch
#define NROW 192000      // input row length (only first 96001 used by irfft)
#define NN   192000      // irfft length
#define N1   512
#define N2   375
#define LP   192512      // padded time length (multiple of HOP)
#define NT   93          // STFT frames
#define NF   2049        // rfft bins of 4096
#define PT   (NT*NF)     // power elems per row = 190557

// Workspace layout (bytes):
//   A : [0, 98304000)                64*512*375 float2  (stage1 out; later aliased by P)
//   P : [0, 48782592)                64*93*2049 float   (power, written after A dead)
//   Y : [98304000, 98304000+49283072)  64*192512 float  (time-domain RIRs, padded)
//   ACC: [147587072, +256)           32*2 float accumulators
#define WS_A_OFF   0
#define WS_Y_OFF   98304000ULL
#define WS_ACC_OFF 147587072ULL

__device__ __forceinline__ float2 cmul(float2 a, float2 b) {
    return make_float2(a.x*b.x - a.y*b.y, a.x*b.y + a.y*b.x);
}
__device__ __forceinline__ float2 cadd(float2 a, float2 b) {
    return make_float2(a.x + b.x, a.y + b.y);
}

// Zero the pad tail of each Y row and the loss accumulators.
__global__ void k_init(float* __restrict__ Y, float* __restrict__ ACC) {
    int i = blockIdx.x * 256 + threadIdx.x;
    if (i < NSIG * 512) {
        int sig = i >> 9, j = i & 511;
        Y[(size_t)sig * LP + NN + j] = 0.f;
    }
    int k = i - NSIG * 512;
    if (k >= 0 && k < 64) ACC[k] = 0.f;
}

// Stage 1: for each (sig, k2): A[t1,k2] = twiddle * IFFT512_{k1}( Xf[375*k1 + k2] )
// Xf is the Hermitian extension of the real one-sided spectrum (imag = 0).
__global__ void __launch_bounds__(256) k_stage1(const float* __restrict__ X0,
                                                const float* __restrict__ X1,
                                                float2* __restrict__ A) {
    const int k2  = blockIdx.x;   // [0,375)
    const int sig = blockIdx.y;   // [0,64)
    const float* X = (sig < 32) ? (X0 + (size_t)sig * NROW)
                                : (X1 + (size_t)(sig - 32) * NROW);
    __shared__ float2 sh[512];
    __shared__ float2 wt[256];    // e^{+2pi i j/512}
    const int tid = threadIdx.x;
    {
        float ang = 6.28318530717958647692f * (float)tid * (1.0f / 512.0f);
        float sn, cs; sincosf(ang, &sn, &cs);
        wt[tid] = make_float2(cs, sn);
    }
    for (int i = tid; i < 512; i += 256) {
        int idx = N2 * i + k2;                       // < 192000
        int src = (idx <= 96000) ? idx : (NN - idx); // Hermitian: X real
        int r = (int)(__brev((unsigned)i) >> 23);    // 9-bit reversal
        sh[r] = make_float2(X[src], 0.f);
    }
    __syncthreads();
    for (int stg = 1; stg <= 9; ++stg) {
        int half = 1 << (stg - 1);
        int j = tid & (half - 1);
        int g = tid >> (stg - 1);
        int i0 = (g << stg) + j;
        int i1 = i0 + half;
        float2 w = wt[j << (9 - stg)];
        float2 u = sh[i0];
        float2 v = cmul(sh[i1], w);
        sh[i0] = make_float2(u.x + v.x, u.y + v.y);
        sh[i1] = make_float2(u.x - v.x, u.y - v.y);
        __syncthreads();
    }
    for (int i = tid; i < 512; i += 256) {
        int r = k2 * i;  // max 374*511 = 191114 < 192000, no mod needed
        float ang = 6.28318530717958647692f * (float)r * (1.0f / 192000.0f);
        float sn, cs; sincosf(ang, &sn, &cs);
        float2 v = cmul(sh[i], make_float2(cs, sn));
        A[((size_t)sig * 512 + i) * N2 + k2] = v;
    }
}

// Stage 2: for each (sig, t1): y[512*t2 + t1] = (1/N) * Re IDFT375_{k2}( A[t1,k2] )
// 375 = 15 x 25 Cooley-Tukey with direct small DFTs; all twiddles from W375 table.
__global__ void __launch_bounds__(128) k_stage2(const float2* __restrict__ A,
                                                float* __restrict__ Y) {
    const int t1  = blockIdx.x;   // [0,512)
    const int sig = blockIdx.y;   // [0,64)
    __shared__ float2 Ain[375];
    __shared__ float2 T1[375];
    __shared__ float2 W[375];     // e^{+2pi i x/375}
    const int tid = threadIdx.x;
    for (int i = tid; i < 375; i += 128) {
        float ang = 6.28318530717958647692f * (float)i * (1.0f / 375.0f);
        float sn, cs; sincosf(ang, &sn, &cs);
        W[i] = make_float2(cs, sn);
        Ain[i] = A[((size_t)sig * 512 + t1) * 375 + i];
    }
    __syncthreads();
    // inner DFT-15 over digit a (k2 = 25a + c), out index e = t2 mod 15
    for (int o = tid; o < 375; o += 128) {
        int e = o / 25, c = o % 25;
        float2 acc = make_float2(0.f, 0.f);
        for (int a = 0; a < 15; ++a) {
            int w15 = (a * e) % 15;
            acc = cadd(acc, cmul(Ain[25 * a + c], W[25 * w15]));
        }
        acc = cmul(acc, W[c * e]);  // c*e <= 24*14 = 336 < 375
        T1[o] = acc;                // o = e*25 + c
    }
    __syncthreads();
    // outer DFT-25 over c, out t2 = 15d + e
    for (int o = tid; o < 375; o += 128) {
        int e = o % 15, d = o / 15;
        float2 acc = make_float2(0.f, 0.f);
        for (int c = 0; c < 25; ++c) {
            int w25 = (c * d) % 25;
            acc = cadd(acc, cmul(T1[e * 25 + c], W[15 * w25]));
        }
        int t2 = 15 * d + e;
        Y[(size_t)sig * LP + (size_t)(512 * t2 + t1)] = acc.x * (1.0f / 192000.0f);
    }
}

// STFT: one block per (frame t, sig). Windowed radix-2 FFT-4096 in LDS, write |S|^2.
// P layout: [sig][t][f], f contiguous (coalesced writes, coalesced EDR reads).
__global__ void __launch_bounds__(256) k_stft(const float* __restrict__ Y,
                                              float* __restrict__ P) {
    const int t   = blockIdx.x;   // [0,93)
    const int sig = blockIdx.y;   // [0,64)
    __shared__ float2 sh[4096];
    __shared__ float2 wt[2048];   // e^{-2pi i j/4096}
    const int tid = threadIdx.x;
    for (int j = tid; j < 2048; j += 256) {
        float ang = -6.28318530717958647692f * (float)j * (1.0f / 4096.0f);
        float sn, cs; sincosf(ang, &sn, &cs);
        wt[j] = make_float2(cs, sn);
    }
    const float* ybase = Y + (size_t)sig * LP + (size_t)t * 2048;
    for (int m = tid; m < 4096; m += 256) {
        float v = ybase[m];
        float w = 0.5f - 0.5f * cosf(6.28318530717958647692f * (float)m * (1.0f / 4096.0f));
        sh[__brev((unsigned)m) >> 20] = make_float2(v * w, 0.f);
    }
    __syncthreads();
    for (int stg = 1; stg <= 12; ++stg) {
        int half = 1 << (stg - 1);
        for (int b = tid; b < 2048; b += 256) {
            int j = b & (half - 1);
            int g = b >> (stg - 1);
            int i0 = (g << stg) + j;
            int i1 = i0 + half;
            float2 w = wt[j << (12 - stg)];
            float2 u = sh[i0];
            float2 v = cmul(sh[i1], w);
            sh[i0] = make_float2(u.x + v.x, u.y + v.y);
            sh[i1] = make_float2(u.x - v.x, u.y - v.y);
        }
        __syncthreads();
    }
    float* pb = P + (size_t)sig * PT + (size_t)t * NF;
    for (int f = tid; f < NF; f += 256) {
        float2 v = sh[f];
        pb[f] = v.x * v.x + v.y * v.y;
    }
}

// EDR + loss partials: block = (f-tile of 256, batch b). Walk t backwards keeping
// suffix power sums (same accumulation order as reference's reversed cumsum).
__global__ void __launch_bounds__(256) k_edr(const float* __restrict__ P,
                                             float* __restrict__ ACC) {
    const int b = blockIdx.y;                      // [0,32)
    const int f = blockIdx.x * 256 + threadIdx.x;  // [0, 2304)
    const bool act = (f < NF);
    const float* Pt = P + (size_t)b * PT;          // target rows 0..31
    const float* Pa = P + (size_t)(b + 32) * PT;   // achieved rows 32..63
    float st = 0.f, sa = 0.f, num = 0.f, den = 0.f;
    if (act) {
        for (int t = NT - 1; t >= 0; --t) {
            st += Pt[(size_t)t * NF + f];
            sa += Pa[(size_t)t * NF + f];
            float et = 10.f * log10f(st);
            float ea = 10.f * log10f(sa);
            num += fabsf(et - ea);
            den += fabsf(et);
        }
    }
    for (int off = 32; off > 0; off >>= 1) {
        num += __shfl_down(num, off);
        den += __shfl_down(den, off);
    }
    __shared__ float sn_[4], sd_[4];
    int wave = threadIdx.x >> 6, lane = threadIdx.x & 63;
    if (lane == 0) { sn_[wave] = num; sd_[wave] = den; }
    __syncthreads();
    if (threadIdx.x == 0) {
        float n = sn_[0] + sn_[1] + sn_[2] + sn_[3];
        float d = sd_[0] + sd_[1] + sd_[2] + sd_[3];
        atomicAdd(&ACC[2 * b], n);
        atomicAdd(&ACC[2 * b + 1], d);
    }
}

__global__ void k_final(const float* __restrict__ ACC, float* __restrict__ out) {
    int tid = threadIdx.x;  // 64 threads
    float r = 0.f;
    if (tid < 32) r = ACC[2 * tid] / ACC[2 * tid + 1];
    for (int off = 32; off > 0; off >>= 1) r += __shfl_down(r, off);
    if (tid == 0) out[0] = r;
}

extern "C" void kernel_launch(void* const* d_in, const int* in_sizes, int n_in,
                              void* d_out, int out_size, void* d_ws, size_t ws_size,
                              hipStream_t stream) {
    const float* X0 = (const float*)d_in[0];  // target_response   [32][192000]
    const float* X1 = (const float*)d_in[1];  // achieved_response [32][192000]
    float* out = (float*)d_out;

    char* base = (char*)d_ws;
    float2* A  = (float2*)(base + WS_A_OFF);
    float*  P  = (float*)(base + WS_A_OFF);   // aliases A; written after A is dead
    float*  Y  = (float*)(base + WS_Y_OFF);
    float*  ACC = (float*)(base + WS_ACC_OFF);

    k_init  <<<dim3(129),      dim3(256), 0, stream>>>(Y, ACC);
    k_stage1<<<dim3(375, 64),  dim3(256), 0, stream>>>(X0, X1, A);
    k_stage2<<<dim3(512, 64),  dim3(128), 0, stream>>>(A, Y);
    k_stft  <<<dim3(93, 64),   dim3(256), 0, stream>>>(Y, P);
    k_edr   <<<dim3(9, 32),    dim3(256), 0, stream>>>(P, ACC);
    k_final <<<1, 64, 0, stream>>>(ACC, out);
}

// Round 2
// 419.207 us; speedup vs baseline: 1.2517x; 1.2517x over previous
//
#include <hip/hip_runtime.h>
#include <math.h>

// Problem constants
#define NSIG 64          // 2 inputs x 32 batch
#define NROW 192000      // input row length
#define NN   192000      // irfft length
#define LP   192512      // padded time length (multiple of HOP)
#define NT   93          // STFT frames
#define NF   2049        // rfft bins of 4096
#define PT   (NT*NF)     // power elems per row = 190557
#define TWO_PI 6.28318530717958647692f

// Workspace layout (bytes):
//   A : [0, 98304000)                  64*375*512 float2 [sig][k2][i]
//   P : [0, 48782592)                  aliases A (written after A dead)
//   Y : [98304000, +49283072)          64*192512 float
//   ACC: [147587072, +256)             32*2 float accumulators
#define WS_A_OFF   0
#define WS_Y_OFF   98304000ULL
#define WS_ACC_OFF 147587072ULL

__device__ __forceinline__ float2 cmul(float2 a, float2 b) {
    return make_float2(a.x*b.x - a.y*b.y, a.x*b.y + a.y*b.x);
}
__device__ __forceinline__ float2 cadd(float2 a, float2 b) {
    return make_float2(a.x + b.x, a.y + b.y);
}

__global__ void k_init(float* __restrict__ Y, float* __restrict__ ACC) {
    int i = blockIdx.x * 256 + threadIdx.x;
    if (i < NSIG * 512) {
        int sig = i >> 9, j = i & 511;
        Y[(size_t)sig * LP + NN + j] = 0.f;
    }
    int k = i - NSIG * 512;
    if (k >= 0 && k < 64) ACC[k] = 0.f;
}

// Stage 1: 15 FFT-512s per block (k2 tile), A[sig][k2][i] written contiguously.
#define TK1 15
#define S1STRIDE 513
__global__ void __launch_bounds__(256) k_stage1(const float* __restrict__ X0,
                                                const float* __restrict__ X1,
                                                float2* __restrict__ A) {
    const int base = blockIdx.x * TK1;  // 25 blocks, exact
    const int sig  = blockIdx.y;
    const float* X = (sig < 32) ? (X0 + (size_t)sig * NROW)
                                : (X1 + (size_t)(sig - 32) * NROW);
    __shared__ float2 sh[TK1 * S1STRIDE];  // 61560 B
    __shared__ float2 wt[256];             // e^{+2pi i j/512}
    const int tid = threadIdx.x;
    const int l   = tid & 15;   // k2 lane (15 used)
    const int g   = tid >> 4;   // 16 butterfly groups
    {
        float ang = TWO_PI * (float)tid * (1.0f / 512.0f);
        float sn, cs; sincosf(ang, &sn, &cs);
        wt[tid] = make_float2(cs, sn);
    }
    const int k2 = base + ((l < TK1) ? l : (TK1 - 1));
    // load + bit-reverse (Hermitian extension of real spectrum)
    for (int i = g; i < 512; i += 16) {
        int idx = 375 * i + k2;
        int src = (idx <= 96000) ? idx : (NN - idx);
        float v = X[src];
        if (l < TK1) {
            int r = (int)(__brev((unsigned)i) >> 23);
            sh[l * S1STRIDE + r] = make_float2(v, 0.f);
        }
    }
    __syncthreads();
    for (int stg = 1; stg <= 9; ++stg) {
        int half = 1 << (stg - 1);
        if (l < TK1) {
            for (int b = g; b < 256; b += 16) {
                int j  = b & (half - 1);
                int gr = b >> (stg - 1);
                int i0 = (gr << stg) + j;
                int i1 = i0 + half;
                float2 w = wt[j << (9 - stg)];
                float2 u = sh[l * S1STRIDE + i0];
                float2 v = cmul(sh[l * S1STRIDE + i1], w);
                sh[l * S1STRIDE + i0] = cadd(u, v);
                sh[l * S1STRIDE + i1] = make_float2(u.x - v.x, u.y - v.y);
            }
        }
        __syncthreads();
    }
    // twiddle + coalesced write of A[sig][k2][i]
    for (int row = 0; row < TK1; ++row) {
        int kk = base + row;
        for (int i = tid; i < 512; i += 256) {
            float ang = TWO_PI * (float)(kk * i) * (1.0f / 192000.0f);
            float sn, cs; sincosf(ang, &sn, &cs);
            float2 v = cmul(sh[row * S1STRIDE + i], make_float2(cs, sn));
            A[((size_t)sig * 375 + kk) * 512 + i] = v;
        }
    }
}

// Stage 2: block = (t1 tile of 16, sig). DFT-375 = 15 x 25 Cooley-Tukey.
// Reads A[sig][k2][t1tile] (contiguous 128B), writes Y[512*t2 + t1tile] (64B runs).
#define TT2 16
__global__ void __launch_bounds__(256) k_stage2(const float2* __restrict__ A,
                                                float* __restrict__ Y) {
    const int t1b = blockIdx.x * TT2;  // 32 blocks
    const int sig = blockIdx.y;
    __shared__ float2 T1s[375 * TT2];  // [e*25+c][t1l], 48000 B
    __shared__ float2 W[375];          // e^{+2pi i x/375}
    const int tid = threadIdx.x;
    for (int i = tid; i < 375; i += 256) {
        float ang = TWO_PI * (float)i * (1.0f / 375.0f);
        float sn, cs; sincosf(ang, &sn, &cs);
        W[i] = make_float2(cs, sn);
    }
    __syncthreads();
    // inner DFT-15 over a (k2 = 25a + c): T1[e][c][t1] = tw * sum_a A[25a+c] W15^{ae}
    for (int w = tid; w < 25 * TT2; w += 256) {
        int c = w >> 4, t1l = w & 15;
        float2 Ain[15];
        const float2* Ab = A + ((size_t)sig * 375 + c) * 512 + t1b + t1l;
        #pragma unroll
        for (int a = 0; a < 15; ++a) Ain[a] = Ab[(size_t)(25 * a) * 512];
        for (int e = 0; e < 15; ++e) {
            float2 acc = Ain[0];
            int idx = 0;
            #pragma unroll
            for (int a = 1; a < 15; ++a) {
                idx += e; if (idx >= 15) idx -= 15;
                acc = cadd(acc, cmul(Ain[a], W[25 * idx]));
            }
            acc = cmul(acc, W[c * e]);  // c*e <= 336
            T1s[(e * 25 + c) * TT2 + t1l] = acc;
        }
    }
    __syncthreads();
    // outer DFT-25 over c: y[15d+e][t1] = Re sum_c T1[e][c][t1] W25^{cd}
    if (tid < 15 * TT2) {
        int e = tid >> 4, t1l = tid & 15;
        float2 Tc[25];
        #pragma unroll
        for (int c = 0; c < 25; ++c) Tc[c] = T1s[(e * 25 + c) * TT2 + t1l];
        float* yb = Y + (size_t)sig * LP + t1b + t1l;
        for (int d = 0; d < 25; ++d) {
            float2 acc = Tc[0];
            int idx = 0;
            #pragma unroll
            for (int c = 1; c < 25; ++c) {
                idx += d; if (idx >= 25) idx -= 25;
                acc = cadd(acc, cmul(Tc[c], W[15 * idx]));
            }
            yb[(size_t)(512 * (15 * d + e))] = acc.x * (1.0f / 192000.0f);
        }
    }
}

// STFT: one block per (frame t, sig). Windowed radix-2 FFT-4096 in LDS, write |S|^2.
__global__ void __launch_bounds__(256) k_stft(const float* __restrict__ Y,
                                              float* __restrict__ P) {
    const int t   = blockIdx.x;   // [0,93)
    const int sig = blockIdx.y;   // [0,64)
    __shared__ float2 sh[4096];
    __shared__ float2 wt[2048];   // e^{-2pi i j/4096}
    const int tid = threadIdx.x;
    for (int j = tid; j < 2048; j += 256) {
        float ang = -TWO_PI * (float)j * (1.0f / 4096.0f);
        float sn, cs; sincosf(ang, &sn, &cs);
        wt[j] = make_float2(cs, sn);
    }
    const float* ybase = Y + (size_t)sig * LP + (size_t)t * 2048;
    for (int m = tid; m < 4096; m += 256) {
        float v = ybase[m];
        float w = 0.5f - 0.5f * cosf(TWO_PI * (float)m * (1.0f / 4096.0f));
        sh[__brev((unsigned)m) >> 20] = make_float2(v * w, 0.f);
    }
    __syncthreads();
    for (int stg = 1; stg <= 12; ++stg) {
        int half = 1 << (stg - 1);
        for (int b = tid; b < 2048; b += 256) {
            int j = b & (half - 1);
            int g = b >> (stg - 1);
            int i0 = (g << stg) + j;
            int i1 = i0 + half;
            float2 w = wt[j << (12 - stg)];
            float2 u = sh[i0];
            float2 v = cmul(sh[i1], w);
            sh[i0] = make_float2(u.x + v.x, u.y + v.y);
            sh[i1] = make_float2(u.x - v.x, u.y - v.y);
        }
        __syncthreads();
    }
    float* pb = P + (size_t)sig * PT + (size_t)t * NF;
    for (int f = tid; f < NF; f += 256) {
        float2 v = sh[f];
        pb[f] = v.x * v.x + v.y * v.y;
    }
}

// EDR + loss partials.
__global__ void __launch_bounds__(256) k_edr(const float* __restrict__ P,
                                             float* __restrict__ ACC) {
    const int b = blockIdx.y;
    const int f = blockIdx.x * 256 + threadIdx.x;
    const bool act = (f < NF);
    const float* Pt = P + (size_t)b * PT;
    const float* Pa = P + (size_t)(b + 32) * PT;
    float st = 0.f, sa = 0.f, num = 0.f, den = 0.f;
    if (act) {
        for (int t = NT - 1; t >= 0; --t) {
            st += Pt[(size_t)t * NF + f];
            sa += Pa[(size_t)t * NF + f];
            float et = 10.f * log10f(st);
            float ea = 10.f * log10f(sa);
            num += fabsf(et - ea);
            den += fabsf(et);
        }
    }
    for (int off = 32; off > 0; off >>= 1) {
        num += __shfl_down(num, off);
        den += __shfl_down(den, off);
    }
    __shared__ float sn_[4], sd_[4];
    int wave = threadIdx.x >> 6, lane = threadIdx.x & 63;
    if (lane == 0) { sn_[wave] = num; sd_[wave] = den; }
    __syncthreads();
    if (threadIdx.x == 0) {
        float n = sn_[0] + sn_[1] + sn_[2] + sn_[3];
        float d = sd_[0] + sd_[1] + sd_[2] + sd_[3];
        atomicAdd(&ACC[2 * b], n);
        atomicAdd(&ACC[2 * b + 1], d);
    }
}

__global__ void k_final(const float* __restrict__ ACC, float* __restrict__ out) {
    int tid = threadIdx.x;
    float r = 0.f;
    if (tid < 32) r = ACC[2 * tid] / ACC[2 * tid + 1];
    for (int off = 32; off > 0; off >>= 1) r += __shfl_down(r, off);
    if (tid == 0) out[0] = r;
}

extern "C" void kernel_launch(void* const* d_in, const int* in_sizes, int n_in,
                              void* d_out, int out_size, void* d_ws, size_t ws_size,
                              hipStream_t stream) {
    const float* X0 = (const float*)d_in[0];
    const float* X1 = (const float*)d_in[1];
    float* out = (float*)d_out;

    char* base = (char*)d_ws;
    float2* A  = (float2*)(base + WS_A_OFF);
    float*  P  = (float*)(base + WS_A_OFF);   // aliases A; written after A is dead
    float*  Y  = (float*)(base + WS_Y_OFF);
    float*  ACC = (float*)(base + WS_ACC_OFF);

    k_init  <<<dim3(129),      dim3(256), 0, stream>>>(Y, ACC);
    k_stage1<<<dim3(25, 64),   dim3(256), 0, stream>>>(X0, X1, A);
    k_stage2<<<dim3(32, 64),   dim3(256), 0, stream>>>(A, Y);
    k_stft  <<<dim3(93, 64),   dim3(256), 0, stream>>>(Y, P);
    k_edr   <<<dim3(9, 32),    dim3(256), 0, stream>>>(P, ACC);
    k_final <<<1, 64, 0, stream>>>(ACC, out);
}

// Round 3
// 296.189 us; speedup vs baseline: 1.7716x; 1.4153x over previous
//
#include <hip/hip_runtime.h>
#include <math.h>

// Problem constants
#define NSIG 64          // 2 inputs x 32 batch
#define NROW 192000      // input row length
#define NN   192000      // irfft length
#define LP   192512      // padded time length (multiple of HOP)
#define NT   93          // STFT frames
#define NF   2049        // rfft bins of 4096
#define PT   (NT*NF)     // power elems per row = 190557
#define TWO_PI 6.28318530717958647692f
#define SQ2H  0.70710678118654752440f

// Workspace layout (bytes):
//   A : [0, 98304000)                  64*375*512 float2 [sig][k2][i]
//   P : [0, 48782592)                  aliases A (written after A dead)
//   Y : [98304000, +49283072)          64*192512 float
//   ACC: [147587072, +256)             32*2 float accumulators
#define WS_A_OFF   0
#define WS_Y_OFF   98304000ULL
#define WS_ACC_OFF 147587072ULL

__device__ __forceinline__ float2 cmul(float2 a, float2 b) {
    return make_float2(a.x*b.x - a.y*b.y, a.x*b.y + a.y*b.x);
}
__device__ __forceinline__ float2 cadd(float2 a, float2 b) {
    return make_float2(a.x + b.x, a.y + b.y);
}
__device__ __forceinline__ float2 csub(float2 a, float2 b) {
    return make_float2(a.x - b.x, a.y - b.y);
}
__device__ __forceinline__ float2 mul_nI(float2 z) { return make_float2(z.y, -z.x); }  // z * -i

// 8-point DFT, time-order in, freq-order out (DIT, fully in registers).
__device__ __forceinline__ void dft8(float2 (&x)[8]) {
    float2 e0 = cadd(x[0], x[4]), e1 = csub(x[0], x[4]);
    float2 e2 = cadd(x[2], x[6]), e3 = csub(x[2], x[6]);
    float2 E0 = cadd(e0, e2), E2 = csub(e0, e2);
    float2 E1 = cadd(e1, mul_nI(e3)), E3 = csub(e1, mul_nI(e3));
    float2 o0 = cadd(x[1], x[5]), o1 = csub(x[1], x[5]);
    float2 o2 = cadd(x[3], x[7]), o3 = csub(x[3], x[7]);
    float2 O0 = cadd(o0, o2), O2 = csub(o0, o2);
    float2 O1 = cadd(o1, mul_nI(o3)), O3 = csub(o1, mul_nI(o3));
    float2 W1 = make_float2(SQ2H*(O1.x + O1.y), SQ2H*(O1.y - O1.x));   // *W8^1
    float2 W2 = mul_nI(O2);                                            // *W8^2
    float2 W3 = make_float2(SQ2H*(O3.y - O3.x), -SQ2H*(O3.x + O3.y));  // *W8^3
    x[0] = cadd(E0, O0); x[4] = csub(E0, O0);
    x[1] = cadd(E1, W1); x[5] = csub(E1, W1);
    x[2] = cadd(E2, W2); x[6] = csub(E2, W2);
    x[3] = cadd(E3, W3); x[7] = csub(E3, W3);
}

__global__ void k_init(float* __restrict__ Y, float* __restrict__ ACC) {
    int i = blockIdx.x * 256 + threadIdx.x;
    if (i < NSIG * 512) {
        int sig = i >> 9, j = i & 511;
        Y[(size_t)sig * LP + NN + j] = 0.f;
    }
    int k = i - NSIG * 512;
    if (k >= 0 && k < 64) ACC[k] = 0.f;
}

// Stage 1: 15 FFT-512s per block (k2 tile), A[sig][k2][i] written contiguously.
#define TK1 15
#define S1STRIDE 513
__global__ void __launch_bounds__(256) k_stage1(const float* __restrict__ X0,
                                                const float* __restrict__ X1,
                                                float2* __restrict__ A) {
    const int base = blockIdx.x * TK1;  // 25 blocks, exact
    const int sig  = blockIdx.y;
    const float* X = (sig < 32) ? (X0 + (size_t)sig * NROW)
                                : (X1 + (size_t)(sig - 32) * NROW);
    __shared__ float2 sh[TK1 * S1STRIDE];  // 61560 B
    __shared__ float2 wt[256];             // e^{+2pi i j/512}
    const int tid = threadIdx.x;
    const int l   = tid & 15;
    const int g   = tid >> 4;
    {
        float ang = TWO_PI * (float)tid * (1.0f / 512.0f);
        float sn, cs; sincosf(ang, &sn, &cs);
        wt[tid] = make_float2(cs, sn);
    }
    const int k2 = base + ((l < TK1) ? l : (TK1 - 1));
    for (int i = g; i < 512; i += 16) {
        int idx = 375 * i + k2;
        int src = (idx <= 96000) ? idx : (NN - idx);
        float v = X[src];
        if (l < TK1) {
            int r = (int)(__brev((unsigned)i) >> 23);
            sh[l * S1STRIDE + r] = make_float2(v, 0.f);
        }
    }
    __syncthreads();
    for (int stg = 1; stg <= 9; ++stg) {
        int half = 1 << (stg - 1);
        if (l < TK1) {
            for (int b = g; b < 256; b += 16) {
                int j  = b & (half - 1);
                int gr = b >> (stg - 1);
                int i0 = (gr << stg) + j;
                int i1 = i0 + half;
                float2 w = wt[j << (9 - stg)];
                float2 u = sh[l * S1STRIDE + i0];
                float2 v = cmul(sh[l * S1STRIDE + i1], w);
                sh[l * S1STRIDE + i0] = cadd(u, v);
                sh[l * S1STRIDE + i1] = make_float2(u.x - v.x, u.y - v.y);
            }
        }
        __syncthreads();
    }
    for (int row = 0; row < TK1; ++row) {
        int kk = base + row;
        for (int i = tid; i < 512; i += 256) {
            float ang = TWO_PI * (float)(kk * i) * (1.0f / 192000.0f);
            float sn, cs; sincosf(ang, &sn, &cs);
            float2 v = cmul(sh[row * S1STRIDE + i], make_float2(cs, sn));
            A[((size_t)sig * 375 + kk) * 512 + i] = v;
        }
    }
}

// Stage 2: block = (t1 tile of 16, sig). DFT-375 = 15 x 25 Cooley-Tukey.
#define TT2 16
__global__ void __launch_bounds__(256) k_stage2(const float2* __restrict__ A,
                                                float* __restrict__ Y) {
    const int t1b = blockIdx.x * TT2;
    const int sig = blockIdx.y;
    __shared__ float2 T1s[375 * TT2];
    __shared__ float2 W[375];
    const int tid = threadIdx.x;
    for (int i = tid; i < 375; i += 256) {
        float ang = TWO_PI * (float)i * (1.0f / 375.0f);
        float sn, cs; sincosf(ang, &sn, &cs);
        W[i] = make_float2(cs, sn);
    }
    __syncthreads();
    for (int w = tid; w < 25 * TT2; w += 256) {
        int c = w >> 4, t1l = w & 15;
        float2 Ain[15];
        const float2* Ab = A + ((size_t)sig * 375 + c) * 512 + t1b + t1l;
        #pragma unroll
        for (int a = 0; a < 15; ++a) Ain[a] = Ab[(size_t)(25 * a) * 512];
        for (int e = 0; e < 15; ++e) {
            float2 acc = Ain[0];
            int idx = 0;
            #pragma unroll
            for (int a = 1; a < 15; ++a) {
                idx += e; if (idx >= 15) idx -= 15;
                acc = cadd(acc, cmul(Ain[a], W[25 * idx]));
            }
            acc = cmul(acc, W[c * e]);
            T1s[(e * 25 + c) * TT2 + t1l] = acc;
        }
    }
    __syncthreads();
    if (tid < 15 * TT2) {
        int e = tid >> 4, t1l = tid & 15;
        float2 Tc[25];
        #pragma unroll
        for (int c = 0; c < 25; ++c) Tc[c] = T1s[(e * 25 + c) * TT2 + t1l];
        float* yb = Y + (size_t)sig * LP + t1b + t1l;
        for (int d = 0; d < 25; ++d) {
            float2 acc = Tc[0];
            int idx = 0;
            #pragma unroll
            for (int c = 1; c < 25; ++c) {
                idx += d; if (idx >= 25) idx -= 25;
                acc = cadd(acc, cmul(Tc[c], W[15 * idx]));
            }
            yb[(size_t)(512 * (15 * d + e))] = acc.x * (1.0f / 192000.0f);
        }
    }
}

// STFT: real-packed FFT-2048 in registers (radix 8,8,8,4), 3 LDS exchanges,
// Hermitian unpack to |rfft_4096|^2. One block per (frame, sig).
__global__ void __launch_bounds__(256) k_stft(const float* __restrict__ Y,
                                              float* __restrict__ P) {
    const int fr  = blockIdx.x;   // [0,93)
    const int sig = blockIdx.y;   // [0,64)
    const int lt  = threadIdx.x;  // [0,256)
    __shared__ float SR[2560], SI[2560];
    float2 x[8];

    // ---- load + window + pack: z[n] = w[2n]y[2n] + i*w[2n+1]y[2n+1], n = lt+256r
    {
        const float2* yb = (const float2*)(Y + (size_t)sig * LP + (size_t)fr * 2048);
        float sn, cs;
        sincosf(TWO_PI * (float)lt * (1.0f / 2048.0f), &sn, &cs);
        float2 ce = make_float2(cs, sn);                       // e^{+i*2pi*lt/2048}
        const float2 d1 = make_float2(0.99999882345170188f,    // e^{+i*pi/2048}
                                      0.00153398018628477f);
        float2 co = cmul(ce, d1);
        const float2 r45 = make_float2(SQ2H, SQ2H);            // e^{+i*pi/4}
        #pragma unroll
        for (int r = 0; r < 8; ++r) {
            float2 v = yb[lt + 256 * r];
            float we = 0.5f - 0.5f * ce.x;
            float wo = 0.5f - 0.5f * co.x;
            x[r] = make_float2(v.x * we, v.y * wo);
            ce = cmul(ce, r45);
            co = cmul(co, r45);
        }
    }
    // ---- stage 1: radix-8 over n2 (stride 256), twiddle W_2048^{lt*k2}
    dft8(x);
    {
        float sn, cs; sincosf(-TWO_PI * (float)lt * (1.0f / 2048.0f), &sn, &cs);
        float2 b = make_float2(cs, sn), tw = b;
        x[1] = cmul(x[1], tw);
        #pragma unroll
        for (int k = 2; k < 8; ++k) { tw = cmul(tw, b); x[k] = cmul(x[k], tw); }
    }
    #pragma unroll
    for (int k = 0; k < 8; ++k) { SR[k * 256 + lt] = x[k].x; SI[k * 256 + lt] = x[k].y; }
    __syncthreads();

    // ---- stage 2: radix-8 over m2, twiddle W_256^{m1*j2}
    {
        const int k2 = lt >> 5, m1 = lt & 31;
        #pragma unroll
        for (int r = 0; r < 8; ++r) {
            int idx = k2 * 256 + m1 + 32 * r;
            x[r] = make_float2(SR[idx], SI[idx]);
        }
        dft8(x);
        float sn, cs; sincosf(-TWO_PI * (float)m1 * (1.0f / 256.0f), &sn, &cs);
        float2 b = make_float2(cs, sn), tw = b;
        x[1] = cmul(x[1], tw);
        #pragma unroll
        for (int k = 2; k < 8; ++k) { tw = cmul(tw, b); x[k] = cmul(x[k], tw); }
        __syncthreads();
        #pragma unroll
        for (int j = 0; j < 8; ++j) {
            int idx = k2 * 288 + j * 36 + m1;   // j2 stride 36: reads spread all banks
            SR[idx] = x[j].x; SI[idx] = x[j].y;
        }
    }
    __syncthreads();

    // ---- stage 3: radix-8 over p2, twiddle W_32^{p1*q2}
    {
        const int k2 = lt >> 5, j2 = (lt >> 2) & 7, p1 = lt & 3;
        #pragma unroll
        for (int r = 0; r < 8; ++r) {
            int idx = k2 * 288 + j2 * 36 + p1 + 4 * r;
            x[r] = make_float2(SR[idx], SI[idx]);
        }
        dft8(x);
        float sn, cs; sincosf(-TWO_PI * (float)p1 * (1.0f / 32.0f), &sn, &cs);
        float2 b = make_float2(cs, sn), tw = b;
        x[1] = cmul(x[1], tw);
        #pragma unroll
        for (int k = 2; k < 8; ++k) { tw = cmul(tw, b); x[k] = cmul(x[k], tw); }
        __syncthreads();
        #pragma unroll
        for (int q = 0; q < 8; ++q) {           // tau = q2*64 + k2*8 + j2 ; idx = 5*tau + p1
            int idx = 5 * (q * 64 + k2 * 8 + j2) + p1;
            SR[idx] = x[q].x; SI[idx] = x[q].y;
        }
    }
    __syncthreads();

    // ---- stage 4: two DFT-4s over p1 (tau = lt and lt+256), write Z[k]
    {
        float2 za[4], zb[4];
        #pragma unroll
        for (int p = 0; p < 4; ++p) {
            int ia = 5 * lt + p;
            za[p] = make_float2(SR[ia], SI[ia]);
            zb[p] = make_float2(SR[ia + 1280], SI[ia + 1280]);
        }
        __syncthreads();
        const int q2a = lt >> 6, k2 = (lt >> 3) & 7, j2 = lt & 7;
        const int kbase = k2 + 8 * j2;
        {
            float2 s0 = cadd(za[0], za[2]), s1 = csub(za[0], za[2]);
            float2 s2 = cadd(za[1], za[3]), s3 = csub(za[1], za[3]);
            float2 X0 = cadd(s0, s2), X2 = csub(s0, s2);
            float2 X1 = cadd(s1, mul_nI(s3)), X3 = csub(s1, mul_nI(s3));
            int ka = kbase + 64 * q2a;
            SR[ka]        = X0.x; SI[ka]        = X0.y;
            SR[ka + 512]  = X1.x; SI[ka + 512]  = X1.y;
            SR[ka + 1024] = X2.x; SI[ka + 1024] = X2.y;
            SR[ka + 1536] = X3.x; SI[ka + 1536] = X3.y;
        }
        {
            float2 s0 = cadd(zb[0], zb[2]), s1 = csub(zb[0], zb[2]);
            float2 s2 = cadd(zb[1], zb[3]), s3 = csub(zb[1], zb[3]);
            float2 X0 = cadd(s0, s2), X2 = csub(s0, s2);
            float2 X1 = cadd(s1, mul_nI(s3)), X3 = csub(s1, mul_nI(s3));
            int kb = kbase + 64 * (q2a + 4);
            SR[kb]        = X0.x; SI[kb]        = X0.y;
            SR[kb + 512]  = X1.x; SI[kb + 512]  = X1.y;
            SR[kb + 1024] = X2.x; SI[kb + 1024] = X2.y;
            SR[kb + 1536] = X3.x; SI[kb + 1536] = X3.y;
        }
    }
    __syncthreads();

    // ---- Hermitian unpack of real FFT + power
    {
        float* pb = P + (size_t)sig * PT + (size_t)fr * NF;
        float sn, cs; sincosf(-TWO_PI * (float)lt * (1.0f / 4096.0f), &sn, &cs);
        float2 wk = make_float2(cs, sn);
        const float2 stp = make_float2(0.92387953251128676f,   // e^{-i*pi/8}
                                       -0.38268343236508977f);
        #pragma unroll
        for (int j = 0; j < 8; ++j) {
            int k  = lt + 256 * j;
            int kc = (2048 - k) & 2047;
            float zr = SR[k],  zi = SI[k];
            float cr = SR[kc], ci = SI[kc];
            float Ex = 0.5f * (zr + cr), Ey = 0.5f * (zi - ci);
            float Ox = 0.5f * (zi + ci), Oy = -0.5f * (zr - cr);
            float Xx = Ex + wk.x * Ox - wk.y * Oy;
            float Xy = Ey + wk.x * Oy + wk.y * Ox;
            pb[k] = Xx * Xx + Xy * Xy;
            wk = cmul(wk, stp);
        }
        if (lt == 0) { float d0 = SR[0] - SI[0]; pb[2048] = d0 * d0; }
    }
}

// EDR + loss partials.
__global__ void __launch_bounds__(256) k_edr(const float* __restrict__ P,
                                             float* __restrict__ ACC) {
    const int b = blockIdx.y;
    const int f = blockIdx.x * 256 + threadIdx.x;
    const bool act = (f < NF);
    const float* Pt = P + (size_t)b * PT;
    const float* Pa = P + (size_t)(b + 32) * PT;
    float st = 0.f, sa = 0.f, num = 0.f, den = 0.f;
    if (act) {
        for (int t = NT - 1; t >= 0; --t) {
            st += Pt[(size_t)t * NF + f];
            sa += Pa[(size_t)t * NF + f];
            float et = 10.f * log10f(st);
            float ea = 10.f * log10f(sa);
            num += fabsf(et - ea);
            den += fabsf(et);
        }
    }
    for (int off = 32; off > 0; off >>= 1) {
        num += __shfl_down(num, off);
        den += __shfl_down(den, off);
    }
    __shared__ float sn_[4], sd_[4];
    int wave = threadIdx.x >> 6, lane = threadIdx.x & 63;
    if (lane == 0) { sn_[wave] = num; sd_[wave] = den; }
    __syncthreads();
    if (threadIdx.x == 0) {
        float n = sn_[0] + sn_[1] + sn_[2] + sn_[3];
        float d = sd_[0] + sd_[1] + sd_[2] + sd_[3];
        atomicAdd(&ACC[2 * b], n);
        atomicAdd(&ACC[2 * b + 1], d);
    }
}

__global__ void k_final(const float* __restrict__ ACC, float* __restrict__ out) {
    int tid = threadIdx.x;
    float r = 0.f;
    if (tid < 32) r = ACC[2 * tid] / ACC[2 * tid + 1];
    for (int off = 32; off > 0; off >>= 1) r += __shfl_down(r, off);
    if (tid == 0) out[0] = r;
}

extern "C" void kernel_launch(void* const* d_in, const int* in_sizes, int n_in,
                              void* d_out, int out_size, void* d_ws, size_t ws_size,
                              hipStream_t stream) {
    const float* X0 = (const float*)d_in[0];
    const float* X1 = (const float*)d_in[1];
    float* out = (float*)d_out;

    char* base = (char*)d_ws;
    float2* A  = (float2*)(base + WS_A_OFF);
    float*  P  = (float*)(base + WS_A_OFF);   // aliases A; written after A is dead
    float*  Y  = (float*)(base + WS_Y_OFF);
    float*  ACC = (float*)(base + WS_ACC_OFF);

    k_init  <<<dim3(129),      dim3(256), 0, stream>>>(Y, ACC);
    k_stage1<<<dim3(25, 64),   dim3(256), 0, stream>>>(X0, X1, A);
    k_stage2<<<dim3(32, 64),   dim3(256), 0, stream>>>(A, Y);
    k_stft  <<<dim3(93, 64),   dim3(256), 0, stream>>>(Y, P);
    k_edr   <<<dim3(9, 32),    dim3(256), 0, stream>>>(P, ACC);
    k_final <<<1, 64, 0, stream>>>(ACC, out);
}